// Round 15
// baseline (541.451 us; speedup 1.0000x reference)
//
#include <hip/hip_runtime.h>

constexpr int IN_F   = 32;
constexpr int OUT_F  = 128;
constexpr int BLOCK  = 256;
constexpr int WAVES  = BLOCK / 64;
constexpr int RSTAGE = 8;

using f32x2  = __attribute__((ext_vector_type(2)))  float;
using f32x4  = __attribute__((ext_vector_type(4)))  float;
using f32x16 = __attribute__((ext_vector_type(16))) float;

// ---------------- R7 kernel (best known: 152.7 us) ----------------
__global__ __launch_bounds__(BLOCK, 4)
void rbf_kernel(const float* __restrict__ x,
                const float* __restrict__ centres,
                const float* __restrict__ log_sigmas,
                float* __restrict__ out,
                int rows_per_wave)
{
    __shared__ float4 xs[WAVES][RSTAGE][IN_F / 4];
    __shared__ float  x2s[WAVES][RSTAGE];

    const int tid = threadIdx.x, wv = tid >> 6, lane = tid & 63;
    const int o0 = lane * 2;
    const f32x16 c0lo = *reinterpret_cast<const f32x16*>(centres + (size_t)(o0+0)*IN_F);
    const f32x16 c0hi = *reinterpret_cast<const f32x16*>(centres + (size_t)(o0+0)*IN_F + 16);
    const f32x16 c1lo = *reinterpret_cast<const f32x16*>(centres + (size_t)(o0+1)*IN_F);
    const f32x16 c1hi = *reinterpret_cast<const f32x16*>(centres + (size_t)(o0+1)*IN_F + 16);

    float c2a = 0.f, c2b = 0.f;
    #pragma unroll
    for (int k = 0; k < 16; ++k) {
        c2a = fmaf(c0lo[k], c0lo[k], c2a); c2a = fmaf(c0hi[k], c0hi[k], c2a);
        c2b = fmaf(c1lo[k], c1lo[k], c2b); c2b = fmaf(c1hi[k], c1hi[k], c2b);
    }
    const float iv0 = __expf(-2.0f * log_sigmas[o0+0]);
    const float iv1 = __expf(-2.0f * log_sigmas[o0+1]);
    const size_t waveRow0 = ((size_t)blockIdx.x * WAVES + wv) * (size_t)rows_per_wave;
    const int rs = lane >> 3, q = lane & 7;

    for (int it = 0; it < rows_per_wave; it += RSTAGE) {
        const float4 v = *reinterpret_cast<const float4*>(x + (waveRow0+it)*IN_F + lane*4);
        float ss = v.x*v.x; ss = fmaf(v.y,v.y,ss); ss = fmaf(v.z,v.z,ss); ss = fmaf(v.w,v.w,ss);
        ss += __shfl_xor(ss,1); ss += __shfl_xor(ss,2); ss += __shfl_xor(ss,4);
        xs[wv][rs][q] = v;
        if (q == 0) x2s[wv][rs] = ss;
        __syncthreads();
        #pragma unroll
        for (int rr = 0; rr < RSTAGE; ++rr) {
            float acc0 = 0.f, acc1 = 0.f;
            #pragma unroll
            for (int u = 0; u < 4; ++u) {
                const float4 xq = xs[wv][rr][u];
                acc0 = fmaf(xq.x,c0lo[4*u+0],acc0); acc0 = fmaf(xq.y,c0lo[4*u+1],acc0);
                acc0 = fmaf(xq.z,c0lo[4*u+2],acc0); acc0 = fmaf(xq.w,c0lo[4*u+3],acc0);
                acc1 = fmaf(xq.x,c1lo[4*u+0],acc1); acc1 = fmaf(xq.y,c1lo[4*u+1],acc1);
                acc1 = fmaf(xq.z,c1lo[4*u+2],acc1); acc1 = fmaf(xq.w,c1lo[4*u+3],acc1);
            }
            #pragma unroll
            for (int u = 0; u < 4; ++u) {
                const float4 xq = xs[wv][rr][4+u];
                acc0 = fmaf(xq.x,c0hi[4*u+0],acc0); acc0 = fmaf(xq.y,c0hi[4*u+1],acc0);
                acc0 = fmaf(xq.z,c0hi[4*u+2],acc0); acc0 = fmaf(xq.w,c0hi[4*u+3],acc0);
                acc1 = fmaf(xq.x,c1hi[4*u+0],acc1); acc1 = fmaf(xq.y,c1hi[4*u+1],acc1);
                acc1 = fmaf(xq.z,c1hi[4*u+2],acc1); acc1 = fmaf(xq.w,c1hi[4*u+3],acc1);
            }
            const float x2 = x2s[wv][rr];
            const float t0 = fmaxf(fmaf(-2.0f,acc0,x2+c2a),0.0f);
            const float t1 = fmaxf(fmaf(-2.0f,acc1,x2+c2b),0.0f);
            f32x2 o; o.x = __expf(-t0*iv0); o.y = __expf(-t1*iv1);
            __builtin_nontemporal_store(o,
                reinterpret_cast<f32x2*>(out + (waveRow0+it+rr)*OUT_F + o0));
        }
        __syncthreads();
    }
}

// -------- mixed-stream probe: idempotent full-buffer self-copy --------
// Reads d_out, launders the value past the optimizer, writes it back.
// 512 MB read + 512 MB write per pass, NT both ways (defeats L3 + DCE).
__global__ __launch_bounds__(BLOCK)
void out_selfcopy(f32x4* __restrict__ p, size_t n4)
{
    const size_t stride = (size_t)gridDim.x * blockDim.x;
    for (size_t i = (size_t)blockIdx.x * blockDim.x + threadIdx.x; i < n4; i += stride) {
        f32x4 v = __builtin_nontemporal_load(&p[i]);
        asm volatile("" : "+v"(v));   // launder: defeat store-of-load elimination
        __builtin_nontemporal_store(v, &p[i]);
    }
}

extern "C" void kernel_launch(void* const* d_in, const int* in_sizes, int n_in,
                              void* d_out, int out_size, void* d_ws, size_t ws_size,
                              hipStream_t stream) {
    const float* x          = (const float*)d_in[0];
    const float* centres    = (const float*)d_in[1];
    const float* log_sigmas = (const float*)d_in[2];
    float* out = (float*)d_out;

    const int n = in_sizes[0] / IN_F;                   // 1,048,576 rows
    const int blocks = 2048;
    const int rows_per_wave = (n / blocks) / WAVES;     // 128

    // dispatch 1: the real kernel (correct output, ~152.7 us)
    rbf_kernel<<<blocks, BLOCK, 0, stream>>>(x, centres, log_sigmas, out, rows_per_wave);

    // dispatches 2+3: pure mixed-stream bandwidth probe (idempotent)
    const size_t n4 = (size_t)out_size / 4;             // 32M f32x4 = 512 MB
    out_selfcopy<<<blocks, BLOCK, 0, stream>>>((f32x4*)d_out, n4);
    out_selfcopy<<<blocks, BLOCK, 0, stream>>>((f32x4*)d_out, n4);
}